// Round 2
// baseline (225.157 us; speedup 1.0000x reference)
//
#include <hip/hip_runtime.h>

#define DEVINL __device__ __forceinline__

DEVINL float fmax4(float4 v) { return fmaxf(fmaxf(v.x, v.y), fmaxf(v.z, v.w)); }
DEVINL float4 max44(float4 a, float4 b) {
    float4 r; r.x = fmaxf(a.x, b.x); r.y = fmaxf(a.y, b.y);
    r.z = fmaxf(a.z, b.z); r.w = fmaxf(a.w, b.w); return r;
}

// Compile-time barrier: pins issue order; loads above cannot sink below.
#define MEMBAR() asm volatile("" ::: "memory")

// ---------------- R7: fully fused single kernel ----------------
// Block (ph, b): computes pooled rows p1[128][28] p2[64][28] p3[32][28]
// p4[16][28] in LDS, then writes out[b,:,ph,:] with ReLU. 224 blocks x 512
// threads (8 waves) -- all blocks resident, no ws round-trip, no 2nd launch.
//
// Work per wave = 15 uniform 1792-float units (107.5 KB):
//   t4: 2 channels x 4 units (16ph..16ph+15 x 448 per ch)
//   t3: 4 channels x 1 unit  (8ph..8ph+7 x 224 per ch)
//   t2: 2 units of 4 packed channels (4ph..4ph+3 x 112 per ch, 448 contig)
//   t1: 1 unit of 16 packed channels (2ph..2ph+1 x 56 per ch, 112 contig)
// Depth-2 pipeline: next unit's 7 float4 loads issued before current unit's
// LDS/gather tail (A/B register buffers).
//
// LDS float layout: P4@0[448] P3@448[896] P2@1344[1792] P1@3136[3584]
//                   scratch@6720: 8 waves x 896
#define P4O 0
#define P3O 448
#define P2O 1344
#define P1O 3136
#define SCRO 6720
#define LDS_FLOATS 13888   // 55.5 KB

#define LD7(DST, PTR)                                                      \
    { _Pragma("unroll") for (int k = 0; k < 7; ++k)                        \
          DST[k] = *(const float4*)((PTR) + k * 256); }

// t2 unit: 4 channels x 448 contiguous floats; float4 f=k*64+lane:
// ch = f/112, within-ch float4 q = f%112.
#define LD7T2(DST, EOFF)                                                   \
    { _Pragma("unroll") for (int k = 0; k < 7; ++k) {                      \
          const int f = k * 64 + lane;                                     \
          DST[k] = *(const float4*)(base2 + (EOFF) + (f / 112) * 12544     \
                                    + (f % 112) * 4); } }

// t1 unit: 16 channels x 112 contiguous floats; ch = f/28, q = f%28.
#define LD7T1(DST)                                                         \
    { _Pragma("unroll") for (int k = 0; k < 7; ++k) {                      \
          const int f = k * 64 + lane;                                     \
          DST[k] = *(const float4*)(base1 + (f / 28) * 3136                \
                                    + (f % 28) * 4); } }

#define ACCSET(V) { _Pragma("unroll") for (int k = 0; k < 7; ++k) acc[k] = V[k]; }
#define ACCMAX(V) { _Pragma("unroll") for (int k = 0; k < 7; ++k) acc[k] = max44(acc[k], V[k]); }

// t4 gather: sm[f] = max over 16 rows (residue r=f/112), cols 4q..4q+3.
// out j = max over r=0..3, q=4j..4j+3.
#define GATH4(E)                                                           \
    { _Pragma("unroll") for (int k = 0; k < 7; ++k)                        \
          sm[k * 64 + lane] = fmax4(acc[k]);                               \
      MEMBAR();                                                            \
      if (lane < 28) {                                                     \
          float4 ga = *(const float4*)&sm[0 * 112 + 4 * lane];             \
          float4 gb = *(const float4*)&sm[1 * 112 + 4 * lane];             \
          float4 gc = *(const float4*)&sm[2 * 112 + 4 * lane];             \
          float4 gd = *(const float4*)&sm[3 * 112 + 4 * lane];             \
          lds[P4O + (2 * ww + (E)) * 28 + lane] =                          \
              fmax4(max44(max44(ga, gb), max44(gc, gd))); } }

// t3: sm[f] = row (f/56) col4 (f%56) max; out j = max 8 rows x col4 {2j,2j+1}
#define T3W(V, H)                                                          \
    { float* smh = sm + (H) * 448;                                         \
      _Pragma("unroll") for (int k = 0; k < 7; ++k)                        \
          smh[k * 64 + lane] = fmax4(V[k]); }
#define T3G(I, H)                                                          \
    { float* smh = sm + (H) * 448;                                         \
      if (lane < 28) {                                                     \
          float2 p0 = *(const float2*)&smh[2 * lane];                      \
          float m = fmaxf(p0.x, p0.y);                                     \
          _Pragma("unroll") for (int r = 1; r < 8; ++r) {                  \
              float2 pr = *(const float2*)&smh[r * 56 + 2 * lane];         \
              m = fmaxf(m, fmaxf(pr.x, pr.y)); }                          \
          lds[P3O + (4 * ww + (I)) * 28 + lane] = m; } }

// t2: sm[f] = per-row col4 max; out (cc,j) = max over 4 rows.
#define T2W(V, H)                                                          \
    { float* smh = sm + (H) * 448;                                         \
      _Pragma("unroll") for (int k = 0; k < 7; ++k)                        \
          smh[k * 64 + lane] = fmax4(V[k]); }
#define T2G(E, H)                                                          \
    { float* smh = sm + (H) * 448;                                         \
      if (lane < 56) {                                                     \
          _Pragma("unroll") for (int h2 = 0; h2 < 2; ++h2) {               \
              const int o = lane + 56 * h2;                                \
              const int cc = o / 28, j = o % 28;                           \
              float m = fmaxf(fmaxf(smh[cc * 112 + 0 * 28 + j],            \
                                    smh[cc * 112 + 1 * 28 + j]),           \
                              fmaxf(smh[cc * 112 + 2 * 28 + j],            \
                                    smh[cc * 112 + 3 * 28 + j]));          \
              lds[P2O + (8 * ww + 4 * (E) + cc) * 28 + j] = m; } } }

// t1: half-max pairs at sm[2f],sm[2f+1] == [cc][row][outcol]; gather rows.
#define T1W(V)                                                             \
    { _Pragma("unroll") for (int k = 0; k < 7; ++k) {                      \
          const int f = k * 64 + lane;                                     \
          float2 hh; hh.x = fmaxf(V[k].x, V[k].y);                         \
          hh.y = fmaxf(V[k].z, V[k].w);                                    \
          *(float2*)&sm[2 * f] = hh; } }
#define T1G()                                                              \
    { _Pragma("unroll") for (int h2 = 0; h2 < 7; ++h2) {                   \
          const int idx = h2 * 64 + lane;                                  \
          const int cc = idx / 28, j = idx % 28;                           \
          lds[P1O + (16 * ww + cc) * 28 + j] =                             \
              fmaxf(sm[cc * 56 + j], sm[cc * 56 + 28 + j]); } }

__global__ __launch_bounds__(512, 2) void fused_all(
    const float* __restrict__ t1, const float* __restrict__ t2,
    const float* __restrict__ t3, const float* __restrict__ t4,
    const float* __restrict__ ff, float* __restrict__ out)
{
    __shared__ __align__(16) float lds[LDS_FLOATS];
    const int tid  = threadIdx.x;
    const int lane = tid & 63;
    const int ww   = tid >> 6;          // 0..7
    const int ph   = blockIdx.x;        // 0..27
    const int b    = blockIdx.y;        // 0..7
    float* sm = &lds[SCRO + ww * 896];

    // ---- ff preload: hides HBM latency under phase 1, held in regs ----
    const float4* FF = (const float4*)ff;
    float4 ffr[4];
    #pragma unroll
    for (int m = 0; m < 3; ++m) {
        const int i4 = tid + 512 * m;
        ffr[m] = FF[(size_t)(b * 256 + i4 / 7) * 196 + ph * 7 + i4 % 7];
    }
    if (tid < 256) {
        const int i4 = tid + 1536;
        ffr[3] = FF[(size_t)(b * 256 + i4 / 7) * 196 + ph * 7 + i4 % 7];
    }

    // per-wave bases
    const float* a4 = t4 + (size_t)b * 3211264 + (2 * ww) * 200704
                    + ph * 16 * 448 + 4 * lane;          // t4 ch 2ww
    const float* b4 = a4 + 200704;                       // t4 ch 2ww+1
    const float* c3 = t3 + (size_t)b * 1605632 + (4 * ww) * 50176
                    + ph * 8 * 224 + 4 * lane;           // t3 ch 4ww..4ww+3
    const float* base2 = t2 + (size_t)b * 802816 + (8 * ww) * 12544
                       + ph * 448;                       // t2 ch 8ww..8ww+7
    const float* base1 = t1 + (size_t)b * 401408 + (16 * ww) * 3136
                       + ph * 112;                       // t1 ch 16ww..16ww+15

    float4 A[7], B[7], acc[7];
    // ---- t4 channel A (4 units, reg-accumulated) ----
    LD7(A, a4);
    LD7(B, a4 + 1792);
    MEMBAR();
    ACCSET(A);
    LD7(A, a4 + 3584); MEMBAR();
    ACCMAX(B);
    LD7(B, a4 + 5376); MEMBAR();
    ACCMAX(A);
    LD7(A, b4); MEMBAR();                 // prefetch t4 ch B unit 0
    ACCMAX(B);
    LD7(B, b4 + 1792); MEMBAR();
    GATH4(0);
    // ---- t4 channel B ----
    ACCSET(A);
    LD7(A, b4 + 3584); MEMBAR();
    ACCMAX(B);
    LD7(B, b4 + 5376); MEMBAR();
    ACCMAX(A);
    LD7(A, c3); MEMBAR();                 // prefetch t3 ch 0
    ACCMAX(B);
    LD7(B, c3 + 50176); MEMBAR();
    GATH4(1);
    // ---- t3 x4 ----
    T3W(A, 0); LD7(A, c3 + 2 * 50176); MEMBAR(); T3G(0, 0);
    T3W(B, 1); LD7(B, c3 + 3 * 50176); MEMBAR(); T3G(1, 1);
    T3W(A, 0); LD7T2(A, 0);            MEMBAR(); T3G(2, 0);
    T3W(B, 1); LD7T2(B, 50176);        MEMBAR(); T3G(3, 1);
    // ---- t2 x2 (4-channel packed units) ----
    T2W(A, 0); LD7T1(A);               MEMBAR(); T2G(0, 0);
    T2W(B, 1);                         MEMBAR(); T2G(1, 1);
    // ---- t1 (16-channel packed unit) ----
    T1W(A); MEMBAR(); T1G();

    __syncthreads();

    // ---- epilogue: out[b,:,ph,:] = relu(p1+p2+p3+p4+ff) ----
    float4* O = (float4*)out;
    #pragma unroll
    for (int m = 0; m < 4; ++m) {
        if (m < 3 || tid < 256) {
            const int i4 = tid + 512 * m;        // 0..1791
            const int ch = i4 / 7, j4 = i4 % 7;
            const float4 x1 = *(const float4*)&lds[P1O + (ch & 127) * 28 + 4 * j4];
            const float4 x2 = *(const float4*)&lds[P2O + (ch & 63)  * 28 + 4 * j4];
            const float4 x3 = *(const float4*)&lds[P3O + (ch & 31)  * 28 + 4 * j4];
            const float4 x4 = *(const float4*)&lds[P4O + (ch & 15)  * 28 + 4 * j4];
            const float4 f  = ffr[m];
            float4 o;
            o.x = fmaxf(x1.x + x2.x + x3.x + x4.x + f.x, 0.0f);
            o.y = fmaxf(x1.y + x2.y + x3.y + x4.y + f.y, 0.0f);
            o.z = fmaxf(x1.z + x2.z + x3.z + x4.z + f.z, 0.0f);
            o.w = fmaxf(x1.w + x2.w + x3.w + x4.w + f.w, 0.0f);
            O[(size_t)(b * 256 + ch) * 196 + ph * 7 + j4] = o;
        }
    }
}

extern "C" void kernel_launch(void* const* d_in, const int* in_sizes, int n_in,
                              void* d_out, int out_size, void* d_ws, size_t ws_size,
                              hipStream_t stream) {
    const float* t1 = (const float*)d_in[0];
    const float* t2 = (const float*)d_in[1];
    const float* t3 = (const float*)d_in[2];
    const float* t4 = (const float*)d_in[3];
    const float* ff = (const float*)d_in[4];
    dim3 grid(28, 8);
    fused_all<<<grid, 512, 0, stream>>>(t1, t2, t3, t4, ff, (float*)d_out);
}

// Round 3
// 223.134 us; speedup vs baseline: 1.0091x; 1.0091x over previous
//
#include <hip/hip_runtime.h>

#define DEVINL __device__ __forceinline__

typedef float f4 __attribute__((ext_vector_type(4)));

DEVINL float fmax4(f4 v) { return fmaxf(fmaxf(v.x, v.y), fmaxf(v.z, v.w)); }
DEVINL f4 max44(f4 a, f4 b) {
    f4 r; r.x = fmaxf(a.x, b.x); r.y = fmaxf(a.y, b.y);
    r.z = fmaxf(a.z, b.z); r.w = fmaxf(a.w, b.w); return r;
}

// ---------------- R8: asm-pinned deep load pipeline ----------------
// R7 post-mortem: VGPR_Count=80 < the 100+ needed for the intended 14-deep
// float4 pipeline => compiler serialized loads to ~2-3 in flight (this is the
// documented HIP-compiler pipelining defeat). Fix: issue every pooling load
// as volatile asm global_load_dwordx4 (issue order = program order), consume
// only after explicit counted s_waitcnt vmcnt(N) + sched_barrier(0).
// Triple buffers A/B/C keep 14-21 loads (56-84 KB/wave) in flight.
//
// Async load: result regs are NOT valid until a VMW() wait executes.
DEVINL f4 ald(const float* p) {
    f4 r;
    asm volatile("global_load_dwordx4 %0, %1, off" : "=v"(r) : "v"(p));
    return r;
}
// Counted wait + full scheduling fence (without sched_barrier the compiler
// hoists register-only consumers above the wait -> reads stale regs).
#define VMW(N)                                                             \
    asm volatile("s_waitcnt vmcnt(" #N ")" ::: "memory");                  \
    __builtin_amdgcn_sched_barrier(0);

// Geometry identical to R7 (verified): block (ph,b), 8 waves, wave ww owns
//   t4 ch {2ww,2ww+1} (4 units each), t3 ch {4ww..4ww+3} (1 unit each),
//   t2 ch {8ww..8ww+7} (2 packed units), t1 ch {16ww..16ww+15} (1 packed unit)
// unit = 1792 contiguous-per-lane floats = 7 asm loads.
//
// LDS float layout: P4@0[448] P3@448[896] P2@1344[1792] P1@3136[3584]
//                   scratch@6720: 8 waves x 896
#define P4O 0
#define P3O 448
#define P2O 1344
#define P1O 3136
#define SCRO 6720
#define LDS_FLOATS 13888   // 55.5 KB

#define LD7G(DST, PTR)                                                     \
    { _Pragma("unroll") for (int k = 0; k < 7; ++k)                        \
          DST[k] = ald((PTR) + k * 256); }

// t2 unit: 4 channels x 448 contiguous floats; f=k*64+lane: ch=f/112, q=f%112
#define LD7T2(DST, EOFF)                                                   \
    { _Pragma("unroll") for (int k = 0; k < 7; ++k) {                      \
          const int f = k * 64 + lane;                                     \
          DST[k] = ald(base2 + (EOFF) + (f / 112) * 12544 + (f % 112) * 4); } }

// t1 unit: 16 channels x 112 contiguous floats; ch=f/28, q=f%28
#define LD7T1(DST)                                                         \
    { _Pragma("unroll") for (int k = 0; k < 7; ++k) {                      \
          const int f = k * 64 + lane;                                     \
          DST[k] = ald(base1 + (f / 28) * 3136 + (f % 28) * 4); } }

#define ACCSET(V) { _Pragma("unroll") for (int k = 0; k < 7; ++k) acc[k] = V[k]; }
#define ACCMAX(V) { _Pragma("unroll") for (int k = 0; k < 7; ++k) acc[k] = max44(acc[k], V[k]); }

// t4 gather: sm[f] = max over 16 rows (residue r=f/112), out j = max r,q=4j..
#define GATH4(E)                                                           \
    { _Pragma("unroll") for (int k = 0; k < 7; ++k)                        \
          sm[k * 64 + lane] = fmax4(acc[k]);                               \
      if (lane < 28) {                                                     \
          f4 ga = *(const f4*)&sm[0 * 112 + 4 * lane];                     \
          f4 gb = *(const f4*)&sm[1 * 112 + 4 * lane];                     \
          f4 gc = *(const f4*)&sm[2 * 112 + 4 * lane];                     \
          f4 gd = *(const f4*)&sm[3 * 112 + 4 * lane];                     \
          lds[P4O + (2 * ww + (E)) * 28 + lane] =                          \
              fmax4(max44(max44(ga, gb), max44(gc, gd))); } }

// t3: sm[f] = row (f/56) col4 (f%56) max; out j = max 8 rows x col4 {2j,2j+1}
#define T3W(V, H)                                                          \
    { float* smh = sm + (H) * 448;                                         \
      _Pragma("unroll") for (int k = 0; k < 7; ++k)                        \
          smh[k * 64 + lane] = fmax4(V[k]); }
#define T3G(I, H)                                                          \
    { float* smh = sm + (H) * 448;                                         \
      if (lane < 28) {                                                     \
          float2 p0 = *(const float2*)&smh[2 * lane];                      \
          float m = fmaxf(p0.x, p0.y);                                     \
          _Pragma("unroll") for (int r = 1; r < 8; ++r) {                  \
              float2 pr = *(const float2*)&smh[r * 56 + 2 * lane];         \
              m = fmaxf(m, fmaxf(pr.x, pr.y)); }                          \
          lds[P3O + (4 * ww + (I)) * 28 + lane] = m; } }

// t2: sm[f] = per-row col4 max; out (cc,j) = max over 4 rows.
#define T2W(V, H)                                                          \
    { float* smh = sm + (H) * 448;                                         \
      _Pragma("unroll") for (int k = 0; k < 7; ++k)                        \
          smh[k * 64 + lane] = fmax4(V[k]); }
#define T2G(E, H)                                                          \
    { float* smh = sm + (H) * 448;                                         \
      if (lane < 56) {                                                     \
          _Pragma("unroll") for (int h2 = 0; h2 < 2; ++h2) {               \
              const int o = lane + 56 * h2;                                \
              const int cc = o / 28, j = o % 28;                           \
              float m = fmaxf(fmaxf(smh[cc * 112 + 0 * 28 + j],            \
                                    smh[cc * 112 + 1 * 28 + j]),           \
                              fmaxf(smh[cc * 112 + 2 * 28 + j],            \
                                    smh[cc * 112 + 3 * 28 + j]));          \
              lds[P2O + (8 * ww + 4 * (E) + cc) * 28 + j] = m; } } }

// t1: half-max pairs sm[2f],sm[2f+1] == [cc][row][outcol]; gather row pairs.
#define T1W(V)                                                             \
    { _Pragma("unroll") for (int k = 0; k < 7; ++k) {                      \
          const int f = k * 64 + lane;                                     \
          float2 hh; hh.x = fmaxf(V[k].x, V[k].y);                         \
          hh.y = fmaxf(V[k].z, V[k].w);                                    \
          *(float2*)&sm[2 * f] = hh; } }
#define T1G()                                                              \
    { _Pragma("unroll") for (int h2 = 0; h2 < 7; ++h2) {                   \
          const int idx = h2 * 64 + lane;                                  \
          const int cc = idx / 28, j = idx % 28;                           \
          lds[P1O + (16 * ww + cc) * 28 + j] =                             \
              fmaxf(sm[cc * 56 + j], sm[cc * 56 + 28 + j]); } }

__global__ __launch_bounds__(512, 2) void fused_all(
    const float* __restrict__ t1, const float* __restrict__ t2,
    const float* __restrict__ t3, const float* __restrict__ t4,
    const float* __restrict__ ff, float* __restrict__ out)
{
    __shared__ __align__(16) float lds[LDS_FLOATS];
    const int tid  = threadIdx.x;
    const int lane = tid & 63;
    const int ww   = tid >> 6;          // 0..7
    const int ph   = blockIdx.x;        // 0..27
    const int b    = blockIdx.y;        // 0..7
    float* sm = &lds[SCRO + ww * 896];

    // ---- ff preload via asm loads, issued FIRST (oldest -> cancels out of
    // all unit wait counts). ffr regs valid after the final VMW(0). ----
    const float* FF = (const float*)ff;
    f4 ffr[4];
    #pragma unroll
    for (int m = 0; m < 4; ++m) {
        const int i4r = tid + 512 * m;
        const int i4 = i4r < 1792 ? i4r : 1791;   // clamp: uniform 4 loads/wave
        ffr[m] = ald(FF + ((size_t)(b * 256 + i4 / 7) * 196 + ph * 7 + i4 % 7) * 4);
    }

    // per-wave bases
    const float* a4 = t4 + (size_t)b * 3211264 + (2 * ww) * 200704
                    + ph * 16 * 448 + 4 * lane;          // t4 ch 2ww
    const float* b4 = a4 + 200704;                       // t4 ch 2ww+1
    const float* c3 = t3 + (size_t)b * 1605632 + (4 * ww) * 50176
                    + ph * 8 * 224 + 4 * lane;           // t3 ch 4ww..4ww+3
    const float* base2 = t2 + (size_t)b * 802816 + (8 * ww) * 12544
                       + ph * 448;                       // t2 ch 8ww..8ww+7
    const float* base1 = t1 + (size_t)b * 401408 + (16 * ww) * 3136
                       + ph * 112;                       // t1 ch 16ww..16ww+15

    f4 A[7], B[7], C[7], acc[7];
    // unit issue ledger (unit loads only; ffr x4 are older and retire first):
    LD7G(A, a4);                //  1-7   t4 chA u0
    LD7G(B, a4 + 1792);         //  8-14  t4 chA u1
    LD7G(C, a4 + 3584);         // 15-21  t4 chA u2
    VMW(14) ACCSET(A);          // A=u0 ready (21-14=7 oldest done)
    LD7G(A, a4 + 5376);         // 22-28  t4 chA u3
    VMW(14) ACCMAX(B);          // B=u1 (28-14=14)
    LD7G(B, b4);                // 29-35  t4 chB u0
    VMW(14) ACCMAX(C);          // C=u2 (35-14=21)
    LD7G(C, b4 + 1792);         // 36-42  t4 chB u1
    VMW(14) ACCMAX(A);          // A=u3 (42-14=28)
    LD7G(A, b4 + 3584);         // 43-49  t4 chB u2
    GATH4(0);
    VMW(14) ACCSET(B);          // B=chB u0 (49-14=35)
    LD7G(B, b4 + 5376);         // 50-56  t4 chB u3
    VMW(14) ACCMAX(C);          // C=chB u1 (56-14=42)
    LD7G(C, c3);                // 57-63  t3 c0
    VMW(14) ACCMAX(A);          // A=chB u2 (63-14=49)
    LD7G(A, c3 + 50176);        // 64-70  t3 c1
    VMW(14) ACCMAX(B);          // B=chB u3 (70-14=56)
    LD7G(B, c3 + 2 * 50176);    // 71-77  t3 c2
    GATH4(1);
    VMW(14) T3W(C, 0);          // C=c0 (77-14=63)
    LD7G(C, c3 + 3 * 50176);    // 78-84  t3 c3
    T3G(0, 0);
    VMW(14) T3W(A, 1);          // A=c1 (84-14=70)
    LD7T2(A, 0);                // 85-91  t2 d0
    T3G(1, 1);
    VMW(14) T3W(B, 0);          // B=c2 (91-14=77)
    LD7T2(B, 50176);            // 92-98  t2 d1
    T3G(2, 0);
    VMW(14) T3W(C, 1);          // C=c3 (98-14=84)
    LD7T1(C);                   // 99-105 t1 e0
    T3G(3, 1);
    VMW(14) T2W(A, 0);          // A=d0 (105-14=91)
    T2G(0, 0);
    VMW(7)  T2W(B, 1);          // B=d1 (105-7=98)
    T2G(1, 1);
    VMW(0)  T1W(C);             // C=e0 + ffr all complete
    T1G();

    __syncthreads();

    // ---- epilogue: out[b,:,ph,:] = relu(p1+p2+p3+p4+ff) ----
    f4* O = (f4*)out;
    #pragma unroll
    for (int m = 0; m < 4; ++m) {
        if (m < 3 || tid < 256) {
            const int i4 = tid + 512 * m;        // 0..1791
            const int ch = i4 / 7, j4 = i4 % 7;
            const f4 x1 = *(const f4*)&lds[P1O + (ch & 127) * 28 + 4 * j4];
            const f4 x2 = *(const f4*)&lds[P2O + (ch & 63)  * 28 + 4 * j4];
            const f4 x3 = *(const f4*)&lds[P3O + (ch & 31)  * 28 + 4 * j4];
            const f4 x4 = *(const f4*)&lds[P4O + (ch & 15)  * 28 + 4 * j4];
            const f4 f  = ffr[m];
            f4 o;
            o.x = fmaxf(x1.x + x2.x + x3.x + x4.x + f.x, 0.0f);
            o.y = fmaxf(x1.y + x2.y + x3.y + x4.y + f.y, 0.0f);
            o.z = fmaxf(x1.z + x2.z + x3.z + x4.z + f.z, 0.0f);
            o.w = fmaxf(x1.w + x2.w + x3.w + x4.w + f.w, 0.0f);
            O[(size_t)(b * 256 + ch) * 196 + ph * 7 + j4] = o;
        }
    }
}

extern "C" void kernel_launch(void* const* d_in, const int* in_sizes, int n_in,
                              void* d_out, int out_size, void* d_ws, size_t ws_size,
                              hipStream_t stream) {
    const float* t1 = (const float*)d_in[0];
    const float* t2 = (const float*)d_in[1];
    const float* t3 = (const float*)d_in[2];
    const float* t4 = (const float*)d_in[3];
    const float* ff = (const float*)d_in[4];
    dim3 grid(28, 8);
    fused_all<<<grid, 512, 0, stream>>>(t1, t2, t3, t4, ff, (float*)d_out);
}

// Round 5
// 200.744 us; speedup vs baseline: 1.1216x; 1.1115x over previous
//
#include <hip/hip_runtime.h>

#define DEVINL __device__ __forceinline__

typedef float f4 __attribute__((ext_vector_type(4)));

DEVINL float fmax4(f4 v) { return fmaxf(fmaxf(v.x, v.y), fmaxf(v.z, v.w)); }
DEVINL f4 max44(f4 a, f4 b) {
    f4 r; r.x = fmaxf(a.x, b.x); r.y = fmaxf(a.y, b.y);
    r.z = fmaxf(a.z, b.z); r.w = fmaxf(a.w, b.w); return r;
}

// Non-temporal (no-allocate) load/store via supported builtins -> `nt` bit.
DEVINL f4 ntld(const float* p) {
    return __builtin_nontemporal_load((const f4*)p);
}

// Compile-time barrier: pins issue order; loads above cannot sink below.
#define MEMBAR() asm volatile("" ::: "memory")

// ---------------- R10: R7 structure + nt cache policy ----------------
// R8 proved pipeline depth (3KB..21KB in flight/wave) does NOT move BW:
// 2.6-2.8 TB/s across R5..R8 => service-rate cap. Hypothesis: L1
// allocate-on-miss throttles single-use streams. Single variable vs R7:
// every input load / output store is non-temporal (no-allocate).
//
// Block (ph, b): pooled rows p1[128][28] p2[64][28] p3[32][28] p4[16][28]
// in LDS, then out[b,:,ph,:] with ReLU. 224 blocks x 512 threads (8 waves).
// Work per wave = 15 uniform 1792-float units (107.5 KB), depth-2 A/B regs.
//
// LDS float layout: P4@0[448] P3@448[896] P2@1344[1792] P1@3136[3584]
//                   scratch@6720: 8 waves x 896
#define P4O 0
#define P3O 448
#define P2O 1344
#define P1O 3136
#define SCRO 6720
#define LDS_FLOATS 13888   // 55.5 KB

#define LD7(DST, PTR)                                                      \
    { _Pragma("unroll") for (int k = 0; k < 7; ++k)                        \
          DST[k] = ntld((PTR) + k * 256); }

// t2 unit: 4 channels x 448 contiguous floats; f=k*64+lane: ch=f/112, q=f%112
#define LD7T2(DST, EOFF)                                                   \
    { _Pragma("unroll") for (int k = 0; k < 7; ++k) {                      \
          const int f = k * 64 + lane;                                     \
          DST[k] = ntld(base2 + (EOFF) + (f / 112) * 12544 + (f % 112) * 4); } }

// t1 unit: 16 channels x 112 contiguous floats; ch=f/28, q=f%28
#define LD7T1(DST)                                                         \
    { _Pragma("unroll") for (int k = 0; k < 7; ++k) {                      \
          const int f = k * 64 + lane;                                     \
          DST[k] = ntld(base1 + (f / 28) * 3136 + (f % 28) * 4); } }

#define ACCSET(V) { _Pragma("unroll") for (int k = 0; k < 7; ++k) acc[k] = V[k]; }
#define ACCMAX(V) { _Pragma("unroll") for (int k = 0; k < 7; ++k) acc[k] = max44(acc[k], V[k]); }

// t4 gather: sm[f] = max over 16 rows (residue r=f/112), out j = max r,q=4j..
#define GATH4(E)                                                           \
    { _Pragma("unroll") for (int k = 0; k < 7; ++k)                        \
          sm[k * 64 + lane] = fmax4(acc[k]);                               \
      MEMBAR();                                                            \
      if (lane < 28) {                                                     \
          f4 ga = *(const f4*)&sm[0 * 112 + 4 * lane];                     \
          f4 gb = *(const f4*)&sm[1 * 112 + 4 * lane];                     \
          f4 gc = *(const f4*)&sm[2 * 112 + 4 * lane];                     \
          f4 gd = *(const f4*)&sm[3 * 112 + 4 * lane];                     \
          lds[P4O + (2 * ww + (E)) * 28 + lane] =                          \
              fmax4(max44(max44(ga, gb), max44(gc, gd))); } }

// t3: sm[f] = row (f/56) col4 (f%56) max; out j = max 8 rows x col4 {2j,2j+1}
#define T3W(V, H)                                                          \
    { float* smh = sm + (H) * 448;                                         \
      _Pragma("unroll") for (int k = 0; k < 7; ++k)                        \
          smh[k * 64 + lane] = fmax4(V[k]); }
#define T3G(I, H)                                                          \
    { float* smh = sm + (H) * 448;                                         \
      if (lane < 28) {                                                     \
          float2 p0 = *(const float2*)&smh[2 * lane];                      \
          float m = fmaxf(p0.x, p0.y);                                     \
          _Pragma("unroll") for (int r = 1; r < 8; ++r) {                  \
              float2 pr = *(const float2*)&smh[r * 56 + 2 * lane];         \
              m = fmaxf(m, fmaxf(pr.x, pr.y)); }                          \
          lds[P3O + (4 * ww + (I)) * 28 + lane] = m; } }

// t2: sm[f] = per-row col4 max; out (cc,j) = max over 4 rows.
#define T2W(V, H)                                                          \
    { float* smh = sm + (H) * 448;                                         \
      _Pragma("unroll") for (int k = 0; k < 7; ++k)                        \
          smh[k * 64 + lane] = fmax4(V[k]); }
#define T2G(E, H)                                                          \
    { float* smh = sm + (H) * 448;                                         \
      if (lane < 56) {                                                     \
          _Pragma("unroll") for (int h2 = 0; h2 < 2; ++h2) {               \
              const int o = lane + 56 * h2;                                \
              const int cc = o / 28, j = o % 28;                           \
              float m = fmaxf(fmaxf(smh[cc * 112 + 0 * 28 + j],            \
                                    smh[cc * 112 + 1 * 28 + j]),           \
                              fmaxf(smh[cc * 112 + 2 * 28 + j],            \
                                    smh[cc * 112 + 3 * 28 + j]));          \
              lds[P2O + (8 * ww + 4 * (E) + cc) * 28 + j] = m; } } }

// t1: half-max pairs sm[2f],sm[2f+1] == [cc][row][outcol]; gather row pairs.
#define T1W(V)                                                             \
    { _Pragma("unroll") for (int k = 0; k < 7; ++k) {                      \
          const int f = k * 64 + lane;                                     \
          float2 hh; hh.x = fmaxf(V[k].x, V[k].y);                         \
          hh.y = fmaxf(V[k].z, V[k].w);                                    \
          *(float2*)&sm[2 * f] = hh; } }
#define T1G()                                                              \
    { _Pragma("unroll") for (int h2 = 0; h2 < 7; ++h2) {                   \
          const int idx = h2 * 64 + lane;                                  \
          const int cc = idx / 28, j = idx % 28;                           \
          lds[P1O + (16 * ww + cc) * 28 + j] =                             \
              fmaxf(sm[cc * 56 + j], sm[cc * 56 + 28 + j]); } }

__global__ __launch_bounds__(512, 2) void fused_all(
    const float* __restrict__ t1, const float* __restrict__ t2,
    const float* __restrict__ t3, const float* __restrict__ t4,
    const float* __restrict__ ff, float* __restrict__ out)
{
    __shared__ __align__(16) float lds[LDS_FLOATS];
    const int tid  = threadIdx.x;
    const int lane = tid & 63;
    const int ww   = tid >> 6;          // 0..7
    const int ph   = blockIdx.x;        // 0..27
    const int b    = blockIdx.y;        // 0..7
    float* sm = &lds[SCRO + ww * 896];

    // ---- ff preload: issued first, held in regs through phase 1 ----
    const float* FF = (const float*)ff;
    f4 ffr[4];
    #pragma unroll
    for (int m = 0; m < 3; ++m) {
        const int i4 = tid + 512 * m;
        ffr[m] = ntld(FF + ((size_t)(b * 256 + i4 / 7) * 196 + ph * 7 + i4 % 7) * 4);
    }
    if (tid < 256) {
        const int i4 = tid + 1536;
        ffr[3] = ntld(FF + ((size_t)(b * 256 + i4 / 7) * 196 + ph * 7 + i4 % 7) * 4);
    }

    // per-wave bases
    const float* a4 = t4 + (size_t)b * 3211264 + (2 * ww) * 200704
                    + ph * 16 * 448 + 4 * lane;          // t4 ch 2ww
    const float* b4 = a4 + 200704;                       // t4 ch 2ww+1
    const float* c3 = t3 + (size_t)b * 1605632 + (4 * ww) * 50176
                    + ph * 8 * 224 + 4 * lane;           // t3 ch 4ww..4ww+3
    const float* base2 = t2 + (size_t)b * 802816 + (8 * ww) * 12544
                       + ph * 448;                       // t2 ch 8ww..8ww+7
    const float* base1 = t1 + (size_t)b * 401408 + (16 * ww) * 3136
                       + ph * 112;                       // t1 ch 16ww..16ww+15

    f4 A[7], B[7], acc[7];
    // ---- t4 channel A (4 units, reg-accumulated) ----
    LD7(A, a4);
    LD7(B, a4 + 1792);
    MEMBAR();
    ACCSET(A);
    LD7(A, a4 + 3584); MEMBAR();
    ACCMAX(B);
    LD7(B, a4 + 5376); MEMBAR();
    ACCMAX(A);
    LD7(A, b4); MEMBAR();                 // prefetch t4 ch B unit 0
    ACCMAX(B);
    LD7(B, b4 + 1792); MEMBAR();
    GATH4(0);
    // ---- t4 channel B ----
    ACCSET(A);
    LD7(A, b4 + 3584); MEMBAR();
    ACCMAX(B);
    LD7(B, b4 + 5376); MEMBAR();
    ACCMAX(A);
    LD7(A, c3); MEMBAR();                 // prefetch t3 ch 0
    ACCMAX(B);
    LD7(B, c3 + 50176); MEMBAR();
    GATH4(1);
    // ---- t3 x4 ----
    T3W(A, 0); LD7(A, c3 + 2 * 50176); MEMBAR(); T3G(0, 0);
    T3W(B, 1); LD7(B, c3 + 3 * 50176); MEMBAR(); T3G(1, 1);
    T3W(A, 0); LD7T2(A, 0);            MEMBAR(); T3G(2, 0);
    T3W(B, 1); LD7T2(B, 50176);        MEMBAR(); T3G(3, 1);
    // ---- t2 x2 (4-channel packed units) ----
    T2W(A, 0); LD7T1(A);               MEMBAR(); T2G(0, 0);
    T2W(B, 1);                         MEMBAR(); T2G(1, 1);
    // ---- t1 (16-channel packed unit) ----
    T1W(A); MEMBAR(); T1G();

    __syncthreads();

    // ---- epilogue: out[b,:,ph,:] = relu(p1+p2+p3+p4+ff), nt stores ----
    f4* O = (f4*)out;
    #pragma unroll
    for (int m = 0; m < 4; ++m) {
        if (m < 3 || tid < 256) {
            const int i4 = tid + 512 * m;        // 0..1791
            const int ch = i4 / 7, j4 = i4 % 7;
            const f4 x1 = *(const f4*)&lds[P1O + (ch & 127) * 28 + 4 * j4];
            const f4 x2 = *(const f4*)&lds[P2O + (ch & 63)  * 28 + 4 * j4];
            const f4 x3 = *(const f4*)&lds[P3O + (ch & 31)  * 28 + 4 * j4];
            const f4 x4 = *(const f4*)&lds[P4O + (ch & 15)  * 28 + 4 * j4];
            const f4 f  = ffr[m];
            f4 o;
            o.x = fmaxf(x1.x + x2.x + x3.x + x4.x + f.x, 0.0f);
            o.y = fmaxf(x1.y + x2.y + x3.y + x4.y + f.y, 0.0f);
            o.z = fmaxf(x1.z + x2.z + x3.z + x4.z + f.z, 0.0f);
            o.w = fmaxf(x1.w + x2.w + x3.w + x4.w + f.w, 0.0f);
            __builtin_nontemporal_store(o, &O[(size_t)(b * 256 + ch) * 196 + ph * 7 + j4]);
        }
    }
}

extern "C" void kernel_launch(void* const* d_in, const int* in_sizes, int n_in,
                              void* d_out, int out_size, void* d_ws, size_t ws_size,
                              hipStream_t stream) {
    const float* t1 = (const float*)d_in[0];
    const float* t2 = (const float*)d_in[1];
    const float* t3 = (const float*)d_in[2];
    const float* t4 = (const float*)d_in[3];
    const float* ff = (const float*)d_in[4];
    dim3 grid(28, 8);
    fused_all<<<grid, 512, 0, stream>>>(t1, t2, t3, t4, ff, (float*)d_out);
}